// Round 11
// baseline (685.718 us; speedup 1.0000x reference)
//
#include <hip/hip_runtime.h>
#include <stdint.h>

#define BATCH 16384
#define IN_DIM 1024
#define HDIM 4096
#define K1 (2 * IN_DIM)  // dual-plane K for gemm1: [a | b] concatenated

// Dual-plane x quantization (r8-proven, absmax 2.0e-3): a = rint(16x)
// (combined range +-7.97 sigma -> zero clipping), b = rint(127*(16x-a)) in
// [-64,64]. x ~= (127a+b)/2032, rep err <= 2.5e-4 (f16-parity).
#define XSTEP 16.0f
#define XDIV  2032.0f  // 127*16

typedef int i32x4 __attribute__((ext_vector_type(4)));
typedef int i32x16 __attribute__((ext_vector_type(16)));

typedef const __attribute__((address_space(1))) void* gas_ptr;
typedef __attribute__((address_space(3))) void* las_ptr;

__device__ __forceinline__ void async_copy16(const void* g, void* l) {
  __builtin_amdgcn_global_load_lds((gas_ptr)g, (las_ptr)l, 16, 0, 0);
}

#define FENCE asm volatile("" ::: "memory")
#define BARRIER do { FENCE; __builtin_amdgcn_s_barrier(); FENCE; } while (0)
#define WAIT_LGKM(N) do { asm volatile("s_waitcnt lgkmcnt(" #N ")" ::: "memory"); \
                          __builtin_amdgcn_sched_barrier(0); } while (0)
#define WAIT_VM(N)   do { asm volatile("s_waitcnt vmcnt(" #N ")" ::: "memory");   \
                          __builtin_amdgcn_sched_barrier(0); } while (0)

// ---------------- prep kernels (r9, unchanged) ----------------

__global__ void cvt_x_dual_kernel(const float* __restrict__ in,
                                  unsigned int* __restrict__ outA, int n4) {
  int i = blockIdx.x * blockDim.x + threadIdx.x;
  if (i < n4) {
    const float4 v = ((const float4*)in)[i];
    const int m = i >> 8;
    const int g = i & 255;
    int a[4], b[4];
    const float xs[4] = {v.x, v.y, v.z, v.w};
#pragma unroll
    for (int t = 0; t < 4; ++t) {
      const float u = xs[t] * XSTEP;
      const float af = rintf(fminf(fmaxf(u, -127.0f), 127.0f));
      float bf = rintf((u - af) * 127.0f);
      bf = fminf(fmaxf(bf, -127.0f), 127.0f);
      a[t] = (int)af;
      b[t] = (int)bf;
    }
    outA[m * 512 + g] =
        (a[0] & 0xffu) | ((a[1] & 0xffu) << 8) | ((a[2] & 0xffu) << 16) | ((a[3] & 0xffu) << 24);
    outA[m * 512 + 256 + g] =
        (b[0] & 0xffu) | ((b[1] & 0xffu) << 8) | ((b[2] & 0xffu) << 16) | ((b[3] & 0xffu) << 24);
  }
}

__global__ void cvt_s_dual_kernel(const int* __restrict__ s1, unsigned int* __restrict__ o1, int n1_4,
                                  const int* __restrict__ s2, unsigned int* __restrict__ o2, int n2_4) {
  int i = blockIdx.x * blockDim.x + threadIdx.x;
  if (i < n1_4) {
    const int4 v = ((const int4*)s1)[i];
    const int n = i >> 8;
    const int g = i & 255;
    const int h0 = 127 * v.x, h1 = 127 * v.y, h2 = 127 * v.z, h3 = 127 * v.w;
    o1[n * 512 + g] =
        (h0 & 0xffu) | ((h1 & 0xffu) << 8) | ((h2 & 0xffu) << 16) | ((h3 & 0xffu) << 24);
    o1[n * 512 + 256 + g] =
        (v.x & 0xffu) | ((v.y & 0xffu) << 8) | ((v.z & 0xffu) << 16) | ((v.w & 0xffu) << 24);
  } else if (i < n1_4 + n2_4) {
    const int j = i - n1_4;
    const int4 v = ((const int4*)s2)[j];
    o2[j] = (v.x & 0xffu) | ((v.y & 0xffu) << 8) | ((v.z & 0xffu) << 16) | ((v.w & 0xffu) << 24);
  }
}

__global__ void scales_init_kernel(const float* __restrict__ ls1, float* __restrict__ s1,
                                   const float* __restrict__ ls2, float* __restrict__ s2,
                                   const float* __restrict__ b_out, float* __restrict__ out,
                                   int out_n) {
  int i = blockIdx.x * blockDim.x + threadIdx.x;
  if (i < out_n) out[i] = b_out[0];
  if (i < HDIM) {
    float l = ls1[i];
    float sp = (l > 20.0f) ? l : log1pf(expf(l));
    s1[i] = fmaxf(sp, 1e-4f) * (1.0f / XDIV);
  } else if (i < 2 * HDIM) {
    float l = ls2[i - HDIM];
    float sp = (l > 20.0f) ? l : log1pf(expf(l));
    s2[i - HDIM] = fmaxf(sp, 1e-4f) * (1.0f / 127.0f);
  }
}

// ---------------- GEMM1 (r9 verbatim: i8 K=2048 dual-plane, 4w@128x128) ----

__global__ __launch_bounds__(256, 1)
void gemm1_kernel(const signed char* __restrict__ A,
                  const signed char* __restrict__ B,
                  const float* __restrict__ scale,   // softplus/2032
                  const float* __restrict__ bias,
                  signed char* __restrict__ Hout) {
  constexpr int K = K1;  // 2048
  extern __shared__ __align__(16) char smem[];
  signed char* const S = (signed char*)smem;

  const int tid = threadIdx.x;
  const int wave = tid >> 6;
  const int lane = tid & 63;
  const int r31 = lane & 31;
  const int half = lane >> 5;
  const int wm = wave >> 1;
  const int wn = wave & 1;
  const int row0 = blockIdx.y * 256;
  const int col0 = blockIdx.x * 256;

  i32x16 acc[4][4];
#pragma unroll
  for (int i = 0; i < 4; ++i)
#pragma unroll
    for (int j = 0; j < 4; ++j)
#pragma unroll
      for (int r = 0; r < 16; ++r) acc[i][j][r] = 0;

  const signed char* Ab = A + (size_t)row0 * K;
  const signed char* Bb = B + (size_t)col0 * K;

  auto stageA = [&](int buf, int k0) {
    signed char* As = S + buf * 32768;
#pragma unroll
    for (int rd = 0; rd < 8; ++rd) {
      const int p = rd * 256 + tid;
      const int r = p >> 3;
      const int c = (p & 7) ^ (r & 7);
      async_copy16(Ab + (size_t)r * K + k0 + c * 16, &As[(rd * 256 + wave * 64) * 16]);
    }
  };
  auto stageB = [&](int buf, int k0) {
    signed char* Bs = S + 65536 + buf * 32768;
#pragma unroll
    for (int rd = 0; rd < 8; ++rd) {
      const int p = rd * 256 + tid;
      const int r = p >> 3;
      const int c = (p & 7) ^ (r & 7);
      async_copy16(Bb + (size_t)r * K + k0 + c * 16, &Bs[(rd * 256 + wave * 64) * 16]);
    }
  };

#define G1_LOAD(SET, S_)                                                     \
  { const int c = (S_) * 2 + half;                                           \
    _Pragma("unroll") for (int i = 0; i < 4; ++i) {                          \
      const int ar = wm * 128 + i * 32 + r31;                                \
      const int cp = c ^ (ar & 7);                                           \
      aF[SET][i] = *(const i32x4*)&As[ar * 128 + cp * 16];                   \
      const int br = wn * 128 + i * 32 + r31;                                \
      const int cq = c ^ (br & 7);                                           \
      bF[SET][i] = *(const i32x4*)&Bs[br * 128 + cq * 16];                   \
    } }
#define G1_MMA(SET)                                                          \
  _Pragma("unroll") for (int i = 0; i < 4; ++i)                              \
    _Pragma("unroll") for (int j = 0; j < 4; ++j)                            \
      acc[i][j] = __builtin_amdgcn_mfma_i32_32x32x32_i8(aF[SET][i], bF[SET][j], acc[i][j], 0, 0, 0);

  constexpr int NT = K / 128;  // 16
  stageA(0, 0);
  stageB(0, 0);
  asm volatile("s_waitcnt vmcnt(0)" ::: "memory");
  BARRIER;

  for (int t = 0; t < NT; ++t) {
    const signed char* As = S + (t & 1) * 32768;
    const signed char* Bs = S + 65536 + (t & 1) * 32768;
    const int nb = (t + 1) & 1;
    const int nk0 = (t + 1) * 128;
    const bool pf = (t + 1 < NT);
    i32x4 aF[2][4], bF[2][4];

    G1_LOAD(0, 0)
    FENCE;
    G1_LOAD(1, 1)
    WAIT_LGKM(8);
    G1_MMA(0)
    if (pf) stageA(nb, nk0);
    G1_LOAD(0, 2)
    WAIT_LGKM(8);
    G1_MMA(1)
    if (pf) stageB(nb, nk0);
    G1_LOAD(1, 3)
    WAIT_LGKM(8);
    G1_MMA(0)
    WAIT_LGKM(0);
    G1_MMA(1)
    asm volatile("s_waitcnt vmcnt(0)" ::: "memory");
    BARRIER;
  }
#undef G1_LOAD
#undef G1_MMA

  // C/D 32x32 layout: col = lane&31, row = (reg&3)+8*(reg>>2)+4*(lane>>5)
#pragma unroll
  for (int j = 0; j < 4; ++j) {
    const int col = col0 + wn * 128 + j * 32 + r31;
    const float sc = scale[col];
    const float bs = bias[col];
#pragma unroll
    for (int i = 0; i < 4; ++i) {
      const int rbase = row0 + wm * 128 + i * 32 + 4 * half;
#pragma unroll
      for (int r = 0; r < 16; ++r) {
        const int row = rbase + (r & 3) + 8 * (r >> 2);
        float v = fminf(fmaxf((float)acc[i][j][r] * sc + bs, -1.0f), 1.0f);
        Hout[(size_t)row * HDIM + col] = (signed char)(int)rintf(v * 127.0f);
      }
    }
  }
}

// ---------------- GEMM2 (r10: i8, 256x256, 8 waves @ 128x64, BK=64, -------
// 4-buffer stage-ahead-3 with COUNTED vmcnt -- the m218 lever).
// Per tile: issue stage(t+3) -> WAIT_VM(12) (t's loads only; 12 stay in
// flight across barriers, never drain-0 in steady state) -> barrier ->
// {6 ds_read kslice0 | 6 ds_read kslice1 | lgkm(6) | setprio 8xMFMA |
// lgkm(0) | setprio 8xMFMA} -> barrier. Legality: stage(t+3) targets
// buf[(t-1)&3]; all readers of it passed the t-1 end-barrier. LDS:
// 4 bufs x (A 16KB + B 16KB) = 128 KB. Swizzle: chunk c of row r at
// slot c^(r&3) (4 chunks/row at BK=64). acc[4][2]=128 regs -> 2 waves/SIMD.

__global__ __launch_bounds__(512, 2)
void gemm2_kernel(const signed char* __restrict__ A,
                  const signed char* __restrict__ B,
                  const float* __restrict__ scale,   // softplus/127
                  const float* __restrict__ bias,
                  const float* __restrict__ w_out,
                  float* __restrict__ out) {
  constexpr int K = HDIM;
  extern __shared__ __align__(16) char smem[];
  signed char* const S = (signed char*)smem;  // buf b: A at b*32768, B at +16384

  const int tid = threadIdx.x;
  const int wave = tid >> 6;
  const int lane = tid & 63;
  const int r31 = lane & 31;
  const int half = lane >> 5;
  const int wm = wave >> 2;   // 0..1 -> 128 rows
  const int wn = wave & 3;    // 0..3 -> 64 cols
  const int row0 = blockIdx.y * 256;
  const int col0 = blockIdx.x * 256;

  i32x16 acc[4][2];
#pragma unroll
  for (int i = 0; i < 4; ++i)
#pragma unroll
    for (int j = 0; j < 2; ++j)
#pragma unroll
      for (int r = 0; r < 16; ++r) acc[i][j][r] = 0;

  const signed char* Ab = A + (size_t)row0 * K;
  const signed char* Bb = B + (size_t)col0 * K;

  // 4 gload_lds per thread per tile (2 rounds A + 2 rounds B, 512 thr x 16 B).
  // A-tile 256 rows x 64 B = 1024 chunks; slot p holds chunk (p&3)^(r&3) of
  // row r=p>>2; DMA dest linear (wave-uniform base + lane*16).
  auto stage = [&](int buf, int k0) {
    signed char* As = S + buf * 32768;
    signed char* Bs = As + 16384;
#pragma unroll
    for (int rd = 0; rd < 2; ++rd) {
      const int p = rd * 512 + tid;
      const int r = p >> 2;
      const int c = (p & 3) ^ (r & 3);
      async_copy16(Ab + (size_t)r * K + k0 + c * 16, &As[(rd * 512 + wave * 64) * 16]);
    }
#pragma unroll
    for (int rd = 0; rd < 2; ++rd) {
      const int p = rd * 512 + tid;
      const int r = p >> 2;
      const int c = (p & 3) ^ (r & 3);
      async_copy16(Bb + (size_t)r * K + k0 + c * 16, &Bs[(rd * 512 + wave * 64) * 16]);
    }
  };

  constexpr int NT = K / 64;  // 64
  stage(0, 0);
  stage(1, 64);
  stage(2, 128);   // 12 loads in flight; t=0 adds 4 then waits vmcnt(12)

  for (int t = 0; t < NT; ++t) {
    const signed char* As = S + (t & 3) * 32768;
    const signed char* Bs = As + 16384;
    if (t + 3 < NT) {
      stage((t + 3) & 3, (t + 3) * 64);
      WAIT_VM(12);          // tile-t's 4 landed; 12 stay in flight
    } else if (t + 3 == NT) {
      WAIT_VM(8);
    } else if (t + 2 == NT) {
      WAIT_VM(4);
    } else {
      WAIT_VM(0);
    }
    BARRIER;                // everyone's tile-t DMA visible

    i32x4 a0[4], b0[2], a1[4], b1[2];
    // kslice 0: chunk c = half; kslice 1: chunk c = 2 + half
#pragma unroll
    for (int i = 0; i < 4; ++i) {
      const int ar = wm * 128 + i * 32 + r31;
      a0[i] = *(const i32x4*)&As[ar * 64 + ((half) ^ (ar & 3)) * 16];
    }
#pragma unroll
    for (int j = 0; j < 2; ++j) {
      const int br = wn * 64 + j * 32 + r31;
      b0[j] = *(const i32x4*)&Bs[br * 64 + ((half) ^ (br & 3)) * 16];
    }
    FENCE;
#pragma unroll
    for (int i = 0; i < 4; ++i) {
      const int ar = wm * 128 + i * 32 + r31;
      a1[i] = *(const i32x4*)&As[ar * 64 + ((2 + half) ^ (ar & 3)) * 16];
    }
#pragma unroll
    for (int j = 0; j < 2; ++j) {
      const int br = wn * 64 + j * 32 + r31;
      b1[j] = *(const i32x4*)&Bs[br * 64 + ((2 + half) ^ (br & 3)) * 16];
    }
    WAIT_LGKM(6);           // kslice-0 set ready; kslice-1 in flight
    __builtin_amdgcn_s_setprio(1);
#pragma unroll
    for (int i = 0; i < 4; ++i)
#pragma unroll
      for (int j = 0; j < 2; ++j)
        acc[i][j] = __builtin_amdgcn_mfma_i32_32x32x32_i8(a0[i], b0[j], acc[i][j], 0, 0, 0);
    __builtin_amdgcn_s_setprio(0);
    WAIT_LGKM(0);
    __builtin_amdgcn_s_setprio(1);
#pragma unroll
    for (int i = 0; i < 4; ++i)
#pragma unroll
      for (int j = 0; j < 2; ++j)
        acc[i][j] = __builtin_amdgcn_mfma_i32_32x32x32_i8(a1[i], b1[j], acc[i][j], 0, 0, 0);
    __builtin_amdgcn_s_setprio(0);
    BARRIER;                // reads of buf[t] done; stage(t+4) may overwrite
  }

  // Fused head: out[row] += sum_col clip(acc*sc+bs)*w_out[col]
#pragma unroll
  for (int i = 0; i < 4; ++i) {
    float rs[16];
#pragma unroll
    for (int r = 0; r < 16; ++r) rs[r] = 0.0f;
#pragma unroll
    for (int j = 0; j < 2; ++j) {
      const int col = col0 + wn * 64 + j * 32 + r31;
      const float sc = scale[col];
      const float bs = bias[col];
      const float w = w_out[col];
#pragma unroll
      for (int r = 0; r < 16; ++r) {
        float v = fminf(fmaxf((float)acc[i][j][r] * sc + bs, -1.0f), 1.0f);
        rs[r] += v * w;
      }
    }
#pragma unroll
    for (int off = 1; off < 32; off <<= 1)
#pragma unroll
      for (int r = 0; r < 16; ++r)
        rs[r] += __shfl_xor(rs[r], off, 64);
    if (r31 == 0) {
      const int rbase = row0 + wm * 128 + i * 32 + 4 * half;
#pragma unroll
      for (int r = 0; r < 16; ++r)
        atomicAdd(&out[rbase + (r & 3) + 8 * (r >> 2)], rs[r]);
    }
  }
}

// ---------------- launch ----------------

extern "C" void kernel_launch(void* const* d_in, const int* in_sizes, int n_in,
                              void* d_out, int out_size, void* d_ws, size_t ws_size,
                              hipStream_t stream) {
  (void)in_sizes; (void)n_in; (void)ws_size;
  const float* x          = (const float*)d_in[0];
  const int*   state1     = (const int*)d_in[1];
  const float* log_scale1 = (const float*)d_in[2];
  const float* bias1      = (const float*)d_in[3];
  const int*   state2     = (const int*)d_in[4];
  const float* log_scale2 = (const float*)d_in[5];
  const float* bias2      = (const float*)d_in[6];
  const float* w_out      = (const float*)d_in[7];
  const float* b_out      = (const float*)d_in[8];
  float* out = (float*)d_out;

  static int lds_attr_done = 0;
  if (!lds_attr_done) {
    hipFuncSetAttribute((const void*)gemm1_kernel,
                        hipFuncAttributeMaxDynamicSharedMemorySize, 131072);
    hipFuncSetAttribute((const void*)gemm2_kernel,
                        hipFuncAttributeMaxDynamicSharedMemorySize, 131072);
    lds_attr_done = 1;
  }

  char* ws = (char*)d_ws;
  signed char* xd  = (signed char*)ws; ws += (size_t)BATCH * K1;       // 32 MB
  signed char* s1d = (signed char*)ws; ws += (size_t)HDIM * K1;        // 8 MB
  signed char* s2q = (signed char*)ws; ws += (size_t)HDIM * HDIM;      // 16 MB
  signed char* h1q = (signed char*)ws; ws += (size_t)BATCH * HDIM;     // 64 MB
  float* scale1 = (float*)ws; ws += HDIM * sizeof(float);
  float* scale2 = (float*)ws; ws += HDIM * sizeof(float);

  const int nx4 = BATCH * IN_DIM / 4;
  const int n1_4 = HDIM * IN_DIM / 4;
  const int n2_4 = HDIM * HDIM / 4;

  cvt_x_dual_kernel<<<(nx4 + 255) / 256, 256, 0, stream>>>(x, (unsigned int*)xd, nx4);
  cvt_s_dual_kernel<<<(n1_4 + n2_4 + 255) / 256, 256, 0, stream>>>(
      state1, (unsigned int*)s1d, n1_4, state2, (unsigned int*)s2q, n2_4);
  const int init_n = (out_size > 2 * HDIM) ? out_size : 2 * HDIM;
  scales_init_kernel<<<(init_n + 255) / 256, 256, 0, stream>>>(
      log_scale1, scale1, log_scale2, scale2, b_out, out, out_size);

  dim3 grid(HDIM / 256, BATCH / 256);  // 16 x 64
  gemm1_kernel<<<grid, 256, 131072, stream>>>(xd, s1d, scale1, bias1, h1q);
  gemm2_kernel<<<grid, 512, 131072, stream>>>(h1q, s2q, scale2, bias2, w_out, out);
}